// Round 1
// baseline (384.512 us; speedup 1.0000x reference)
//
#include <hip/hip_runtime.h>

#define TOPK 32
#define EMB 64
#define NPT 4      // nodes per 8-lane group in the sliced gather

// =====================================================================
// k0: block-partial |max| over emb. 1024 partials, no atomics (deterministic).
// =====================================================================
__global__ __launch_bounds__(256) void absmax_partial_kernel(
    const float* __restrict__ emb, float* __restrict__ partial, int total4)
{
    const float4* src = (const float4*)emb;
    float m = 0.0f;
    for (int i = blockIdx.x * 256 + threadIdx.x; i < total4; i += gridDim.x * 256) {
        float4 v = src[i];
        m = fmaxf(m, fmaxf(fmaxf(fabsf(v.x), fabsf(v.y)),
                           fmaxf(fabsf(v.z), fabsf(v.w))));
    }
    __shared__ float red[256];
    red[threadIdx.x] = m;
    __syncthreads();
    for (int s = 128; s > 0; s >>= 1) {
        if (threadIdx.x < s) red[threadIdx.x] = fmaxf(red[threadIdx.x], red[threadIdx.x + s]);
        __syncthreads();
    }
    if (threadIdx.x == 0) partial[blockIdx.x] = red[0];
}

// =====================================================================
// k1: every block redundantly reduces the 1024 partials -> global max.
//  blocks [0, a_blocks): quantize emb fp32 -> int8 (16 elems/thread)
//  block  a_blocks:      zero row at index N (exactly 64B!) + store step
// =====================================================================
__global__ __launch_bounds__(256) void quant_kernel(
    const float* __restrict__ emb, signed char* __restrict__ emb8,
    const float* __restrict__ partial, float* __restrict__ stepOut,
    int n_nodes, int a_blocks)
{
    const int t = threadIdx.x;
    __shared__ float red[256];
    float m = fmaxf(fmaxf(partial[t], partial[t + 256]),
                    fmaxf(partial[t + 512], partial[t + 768]));
    red[t] = m;
    __syncthreads();
    for (int s = 128; s > 0; s >>= 1) {
        if (t < s) red[t] = fmaxf(red[t], red[t + s]);
        __syncthreads();
    }
    const float maxv = fmaxf(red[0], 1e-20f);
    const float inv_step = 127.0f / maxv;

    if ((int)blockIdx.x < a_blocks) {
        const int gid = blockIdx.x * 256 + t;              // 16 elems per thread
        const int total16 = n_nodes * (EMB / 16);
        if (gid < total16) {
            const float4* src = (const float4*)emb + (size_t)gid * 4;
            unsigned int w[4];
            #pragma unroll
            for (int p = 0; p < 4; ++p) {
                float4 v = src[p];
                int q0 = (int)__builtin_rintf(fminf(fmaxf(v.x * inv_step, -127.f), 127.f));
                int q1 = (int)__builtin_rintf(fminf(fmaxf(v.y * inv_step, -127.f), 127.f));
                int q2 = (int)__builtin_rintf(fminf(fmaxf(v.z * inv_step, -127.f), 127.f));
                int q3 = (int)__builtin_rintf(fminf(fmaxf(v.w * inv_step, -127.f), 127.f));
                w[p] = (unsigned int)(q0 & 0xff) | ((unsigned int)(q1 & 0xff) << 8) |
                       ((unsigned int)(q2 & 0xff) << 16) | ((unsigned int)(q3 & 0xff) << 24);
            }
            ((int4*)emb8)[gid] = make_int4((int)w[0], (int)w[1], (int)w[2], (int)w[3]);
        }
    } else {
        // zero row = 64 bytes = exactly 4 int4
        if (t < 4)
            ((int4*)(emb8 + (size_t)n_nodes * EMB))[t] = make_int4(0, 0, 0, 0);
        if (t == 0) stepOut[0] = maxv / 127.0f;
    }
}

// =====================================================================
// k2: slice-phased gather.
//  - 8 lanes per node-group; each group owns NPT=4 nodes (grid co-resident).
//  - Per group: bucket the 4x32 neighbor indices by table slice (2MB slices)
//    into LDS via an intra-wave counting sort (no barriers needed: all LDS
//    traffic for a group comes from its own 8 lanes, same wave).
//  - Slice loop outermost: all resident blocks walk slices in the same order
//    so each 2MB slice stays L2-resident for all of its uses.
//  - Accumulation identical to the proven kernel: exact int32, 8B/lane rows.
// =====================================================================
#define ACC8(A, rx, ry) do {                                \
    A[0] += (int)(signed char)((rx) & 0xff);                \
    A[1] += (int)(signed char)(((rx) >> 8) & 0xff);         \
    A[2] += (int)(signed char)(((rx) >> 16) & 0xff);        \
    A[3] += ((int)(rx)) >> 24;                              \
    A[4] += (int)(signed char)((ry) & 0xff);                \
    A[5] += (int)(signed char)(((ry) >> 8) & 0xff);         \
    A[6] += (int)(signed char)(((ry) >> 16) & 0xff);        \
    A[7] += ((int)(ry)) >> 24; } while (0)

__global__ __launch_bounds__(256, 6) void gather_q8_sliced_kernel(
    const signed char* __restrict__ emb8,
    const float* __restrict__ wei,
    const int*   __restrict__ nei,
    const float* __restrict__ stepPtr,
    float*       __restrict__ out,
    int n_nodes, int n_groups, int sshift, int nslices)
{
    __shared__ int s_cur[32][NPT][8];    // per (group,node): slice offsets, 4KB
    __shared__ int s_lst[32][NPT][32];   // bucketed (pre-shifted) row offsets, 16KB

    const int gl   = threadIdx.x >> 3;   // group within block, 0..31
    const int lane = threadIdx.x & 7;    // lane within group
    const int g    = blockIdx.x * 32 + gl;
    if (g >= n_groups) return;           // whole group uniform; no barriers used

    // zero slice counters (own group only -> same wave, no sync needed)
    #pragma unroll
    for (int m = 0; m < NPT; ++m) s_cur[gl][m][lane] = 0;

    // load nei/wei; masked or out-of-range -> -1
    int jm[NPT][4];
    #pragma unroll
    for (int m = 0; m < NPT; ++m) {
        const int n = g + m * n_groups;
        if (n < n_nodes) {
            const long base = (long)n * TOPK;
            const int4   j4 = *(const int4*)(nei + base + lane * 4);
            const float4 w4 = *(const float4*)(wei + base + lane * 4);
            jm[m][0] = (w4.x != 0.0f) ? j4.x : -1;
            jm[m][1] = (w4.y != 0.0f) ? j4.y : -1;
            jm[m][2] = (w4.z != 0.0f) ? j4.z : -1;
            jm[m][3] = (w4.w != 0.0f) ? j4.w : -1;
        } else {
            jm[m][0] = jm[m][1] = jm[m][2] = jm[m][3] = -1;
        }
    }

    // pass 1: per-slice counts (LDS atomics, intra-wave)
    #pragma unroll
    for (int m = 0; m < NPT; ++m) {
        #pragma unroll
        for (int c = 0; c < 4; ++c) {
            const int v = jm[m][c];
            if (v >= 0) atomicAdd(&s_cur[gl][m][v >> sshift], 1);
        }
    }

    // lane 0: exclusive prefix -> start offsets; tot = valid-neighbor count
    int tot[NPT] = {0, 0, 0, 0};
    if (lane == 0) {
        #pragma unroll
        for (int m = 0; m < NPT; ++m) {
            int run = 0;
            for (int s = 0; s < nslices; ++s) {
                const int t = s_cur[gl][m][s];
                s_cur[gl][m][s] = run;
                run += t;
            }
            tot[m] = run;
        }
    }
    #pragma unroll
    for (int m = 0; m < NPT; ++m) tot[m] = __shfl(tot[m], 0, 8);

    // pass 2: place items (store pre-shifted byte offsets, j*64)
    #pragma unroll
    for (int m = 0; m < NPT; ++m) {
        #pragma unroll
        for (int c = 0; c < 4; ++c) {
            const int v = jm[m][c];
            if (v >= 0) {
                const int pos = atomicAdd(&s_cur[gl][m][v >> sshift], 1);
                s_lst[gl][m][pos] = v << 6;
            }
        }
    }
    // s_cur[gl][m][s] now holds END offset of slice s

    int acc[NPT][8];
    #pragma unroll
    for (int m = 0; m < NPT; ++m)
        #pragma unroll
        for (int e = 0; e < 8; ++e) acc[m][e] = 0;

    const signed char* ebase = emb8 + lane * 8;

    for (int s = 0; s < nslices; ++s) {
        #pragma unroll
        for (int m = 0; m < NPT; ++m) {
            int i = (s == 0) ? 0 : s_cur[gl][m][s - 1];
            const int e = s_cur[gl][m][s];
            // 4-wide chunks for MLP
            for (; i + 4 <= e; i += 4) {
                const int o0 = s_lst[gl][m][i];
                const int o1 = s_lst[gl][m][i + 1];
                const int o2 = s_lst[gl][m][i + 2];
                const int o3 = s_lst[gl][m][i + 3];
                const uint2 r0 = *(const uint2*)(ebase + o0);
                const uint2 r1 = *(const uint2*)(ebase + o1);
                const uint2 r2 = *(const uint2*)(ebase + o2);
                const uint2 r3 = *(const uint2*)(ebase + o3);
                ACC8(acc[m], r0.x, r0.y);
                ACC8(acc[m], r1.x, r1.y);
                ACC8(acc[m], r2.x, r2.y);
                ACC8(acc[m], r3.x, r3.y);
            }
            for (; i < e; ++i) {
                const int o = s_lst[gl][m][i];
                const uint2 r = *(const uint2*)(ebase + o);
                ACC8(acc[m], r.x, r.y);
            }
        }
    }

    const float step = stepPtr[0];
    #pragma unroll
    for (int m = 0; m < NPT; ++m) {
        const int n = g + m * n_groups;
        if (n < n_nodes) {
            const float mlt = step / ((float)tot[m] + 1e-12f);
            float4 o0, o1;
            o0.x = acc[m][0] * mlt; o0.y = acc[m][1] * mlt;
            o0.z = acc[m][2] * mlt; o0.w = acc[m][3] * mlt;
            o1.x = acc[m][4] * mlt; o1.y = acc[m][5] * mlt;
            o1.z = acc[m][6] * mlt; o1.w = acc[m][7] * mlt;
            float* op = out + (size_t)n * EMB + lane * 8;
            *(float4*)op       = o0;
            *(float4*)(op + 4) = o1;
        }
    }
}

// =====================================================================
// Fallback (tiny ws): verified R0 fp32 kernel
// =====================================================================
__global__ __launch_bounds__(256) void pprgo_f32_kernel(
    const float* __restrict__ emb,
    const float* __restrict__ wei,
    const int*   __restrict__ nei,
    float*       __restrict__ out,
    int n_nodes)
{
    const int tid   = blockIdx.x * blockDim.x + threadIdx.x;
    const int group = tid >> 4;
    const int lane  = tid & 15;
    if (group >= n_nodes) return;
    const long base = (long)group * TOPK;
    const float w0 = wei[base + lane];
    const float w1 = wei[base + 16 + lane];
    const int   i0 = nei[base + lane];
    const int   i1 = nei[base + 16 + lane];
    const float m0 = (w0 != 0.0f) ? 1.0f : 0.0f;
    const float m1 = (w1 != 0.0f) ? 1.0f : 0.0f;
    float4 acc = make_float4(0.f, 0.f, 0.f, 0.f);
    float  cnt = 0.0f;
    #pragma unroll 8
    for (int k = 0; k < 16; ++k) {
        const int   j0 = __shfl(i0, k, 16);
        const float a0 = __shfl(m0, k, 16);
        const float4 r0 = *(const float4*)(emb + (size_t)j0 * EMB + lane * 4);
        acc.x += a0*r0.x; acc.y += a0*r0.y; acc.z += a0*r0.z; acc.w += a0*r0.w; cnt += a0;
        const int   j1 = __shfl(i1, k, 16);
        const float a1 = __shfl(m1, k, 16);
        const float4 r1 = *(const float4*)(emb + (size_t)j1 * EMB + lane * 4);
        acc.x += a1*r1.x; acc.y += a1*r1.y; acc.z += a1*r1.z; acc.w += a1*r1.w; cnt += a1;
    }
    const float sc = 1.0f / (cnt + 1e-12f);
    float4 o;
    o.x = acc.x*sc; o.y = acc.y*sc; o.z = acc.z*sc; o.w = acc.w*sc;
    *(float4*)(out + (size_t)group * EMB + lane * 4) = o;
}

extern "C" void kernel_launch(void* const* d_in, const int* in_sizes, int n_in,
                              void* d_out, int out_size, void* d_ws, size_t ws_size,
                              hipStream_t stream) {
    const float* emb = (const float*)d_in[0];   // [N, 64] fp32
    const float* wei = (const float*)d_in[1];   // [N, 32] fp32
    const int*   nei = (const int*)d_in[2];     // [N, 32] int32
    float*       out = (float*)d_out;           // [N, 1, 64] fp32

    const int n_nodes = in_sizes[1] / TOPK;     // 200000

    const size_t emb8_bytes  = (size_t)(n_nodes + 1) * EMB;            // 12.8MB + 64B
    const size_t partial_off = (emb8_bytes + 15) & ~(size_t)15;
    const size_t need_q8     = partial_off + 1024 * sizeof(float) + 16;

    if (ws_size >= need_q8) {
        signed char* emb8    = (signed char*)d_ws;
        float*       partial = (float*)((char*)d_ws + partial_off);
        float*       stepP   = partial + 1024;

        const int total4 = n_nodes * EMB / 4;
        absmax_partial_kernel<<<1024, 256, 0, stream>>>(emb, partial, total4);

        const int a_blocks = (n_nodes * (EMB / 16) + 255) / 256;       // 3125
        quant_kernel<<<a_blocks + 1, 256, 0, stream>>>(
            emb, emb8, partial, stepP, n_nodes, a_blocks);

        // slice-phased gather: slices of 2^sshift rows (<=8 slices, <=2MB each
        // for N=200000 -> 7 slices), grid sized so all blocks are co-resident.
        const int n_groups = (n_nodes + NPT - 1) / NPT;                // 50000
        int sshift = 15;
        while (((n_nodes + (1 << sshift) - 1) >> sshift) > 8) ++sshift;
        const int nslices = (n_nodes + (1 << sshift) - 1) >> sshift;   // 7
        const int g_blocks = (n_groups + 31) / 32;                     // 1563
        gather_q8_sliced_kernel<<<g_blocks, 256, 0, stream>>>(
            emb8, wei, nei, stepP, out, n_nodes, n_groups, sshift, nslices);
    } else {
        const int threads = n_nodes * 16;
        pprgo_f32_kernel<<<(threads + 255) / 256, 256, 0, stream>>>(
            emb, wei, nei, out, n_nodes);
    }
}

// Round 2
// 225.352 us; speedup vs baseline: 1.7063x; 1.7063x over previous
//
#include <hip/hip_runtime.h>

#define TOPK 32
#define EMB 64

// =====================================================================
// k1: fused per-row quantization. 4 lanes per 64-float row, row absmax via
// two shfl_xor, quantize fp32 -> int8, store row scale. One pass over emb,
// no global reduction, no second kernel. Row N (zero row) gets scale 0.
// =====================================================================
__global__ __launch_bounds__(256) void quant_rowscale_kernel(
    const float* __restrict__ emb, signed char* __restrict__ emb8,
    float* __restrict__ scaleP, int n_nodes)
{
    const int t   = threadIdx.x;
    const int row = blockIdx.x * 64 + (t >> 2);   // 64 rows per block
    const int q   = t & 3;                        // quarter of the row
    if (row > n_nodes) return;

    if (row == n_nodes) {
        // sentinel zero row: 64 bytes = 4 int4, scale 0
        ((int4*)(emb8 + (size_t)n_nodes * EMB))[q] = make_int4(0, 0, 0, 0);
        if (q == 0) scaleP[n_nodes] = 0.0f;
        return;
    }

    const float4* src = (const float4*)(emb + (size_t)row * EMB + q * 16);
    float4 v[4];
    v[0] = src[0]; v[1] = src[1]; v[2] = src[2]; v[3] = src[3];

    float m = 0.0f;
    #pragma unroll
    for (int p = 0; p < 4; ++p)
        m = fmaxf(m, fmaxf(fmaxf(fabsf(v[p].x), fabsf(v[p].y)),
                           fmaxf(fabsf(v[p].z), fabsf(v[p].w))));
    // reduce across the 4 lanes owning this row
    m = fmaxf(m, __shfl_xor(m, 1, 4));
    m = fmaxf(m, __shfl_xor(m, 2, 4));

    const float maxv = fmaxf(m, 1e-20f);
    const float inv_step = 127.0f / maxv;

    unsigned int w[4];
    #pragma unroll
    for (int p = 0; p < 4; ++p) {
        int q0 = (int)__builtin_rintf(fminf(fmaxf(v[p].x * inv_step, -127.f), 127.f));
        int q1 = (int)__builtin_rintf(fminf(fmaxf(v[p].y * inv_step, -127.f), 127.f));
        int q2 = (int)__builtin_rintf(fminf(fmaxf(v[p].z * inv_step, -127.f), 127.f));
        int q3 = (int)__builtin_rintf(fminf(fmaxf(v[p].w * inv_step, -127.f), 127.f));
        w[p] = (unsigned int)(q0 & 0xff) | ((unsigned int)(q1 & 0xff) << 8) |
               ((unsigned int)(q2 & 0xff) << 16) | ((unsigned int)(q3 & 0xff) << 24);
    }
    ((int4*)(emb8 + (size_t)row * EMB))[q] =
        make_int4((int)w[0], (int)w[1], (int)w[2], (int)w[3]);
    if (q == 0) scaleP[row] = maxv * (1.0f / 127.0f);
}

// =====================================================================
// k2: gather. R0's proven shape: 8 lanes/node, inline mask (masked -> row N
// of zeros, scale 0), 32 x 64B row gathers (uint2/lane). Per-row scale is
// shuffled alongside the index and folded in with fma (fp32 accumulate,
// fixed order -> deterministic).
// =====================================================================
__global__ __launch_bounds__(256) void gather_q8s_kernel(
    const signed char* __restrict__ emb8,
    const float* __restrict__ scaleP,
    const float* __restrict__ wei,
    const int*   __restrict__ nei,
    float*       __restrict__ out,
    int n_nodes)
{
    const int tid  = blockIdx.x * 256 + threadIdx.x;
    const int n    = tid >> 3;
    const int lane = tid & 7;
    if (n >= n_nodes) return;

    const long base = (long)n * TOPK;
    const int4   j4 = *(const int4*)(nei + base + lane * 4);
    const float4 w4 = *(const float4*)(wei + base + lane * 4);
    int jm[4];
    jm[0] = (w4.x != 0.0f) ? j4.x : n_nodes;
    jm[1] = (w4.y != 0.0f) ? j4.y : n_nodes;
    jm[2] = (w4.z != 0.0f) ? j4.z : n_nodes;
    jm[3] = (w4.w != 0.0f) ? j4.w : n_nodes;

    // per-neighbor row scales (scaleP[n_nodes] == 0 for masked)
    float sm[4];
    sm[0] = scaleP[jm[0]];
    sm[1] = scaleP[jm[1]];
    sm[2] = scaleP[jm[2]];
    sm[3] = scaleP[jm[3]];

    float acc[8] = {0.f, 0.f, 0.f, 0.f, 0.f, 0.f, 0.f, 0.f};
    int cnt = 0;

    #pragma unroll
    for (int t2 = 0; t2 < 4; ++t2) {
        // row r = t2*8 + k lives in lane 2*t2 + (k>>2), component k&3
        int   j[8];
        float sc[8];
        #pragma unroll
        for (int k = 0; k < 8; ++k) {
            j[k]  = __shfl(jm[k & 3], t2 * 2 + (k >> 2), 8);
            sc[k] = __shfl(sm[k & 3], t2 * 2 + (k >> 2), 8);
        }
        uint2 r[8];
        #pragma unroll
        for (int k = 0; k < 8; ++k)
            r[k] = *(const uint2*)(emb8 + (size_t)j[k] * EMB + lane * 8);
        #pragma unroll
        for (int k = 0; k < 8; ++k) {
            cnt += (j[k] != n_nodes) ? 1 : 0;
            const unsigned int x = r[k].x, y = r[k].y;
            const float s = sc[k];
            acc[0] += s * (float)(int)(signed char)(x & 0xff);
            acc[1] += s * (float)(int)(signed char)((x >> 8) & 0xff);
            acc[2] += s * (float)(int)(signed char)((x >> 16) & 0xff);
            acc[3] += s * (float)(((int)x) >> 24);
            acc[4] += s * (float)(int)(signed char)(y & 0xff);
            acc[5] += s * (float)(int)(signed char)((y >> 8) & 0xff);
            acc[6] += s * (float)(int)(signed char)((y >> 16) & 0xff);
            acc[7] += s * (float)(((int)y) >> 24);
        }
    }

    const float mlt = 1.0f / ((float)cnt + 1e-12f);
    float4 o0, o1;
    o0.x = acc[0] * mlt; o0.y = acc[1] * mlt; o0.z = acc[2] * mlt; o0.w = acc[3] * mlt;
    o1.x = acc[4] * mlt; o1.y = acc[5] * mlt; o1.z = acc[6] * mlt; o1.w = acc[7] * mlt;
    float* op = out + (size_t)n * EMB + lane * 8;
    *(float4*)op       = o0;
    *(float4*)(op + 4) = o1;
}

// =====================================================================
// Fallback (tiny ws): verified R0 fp32 kernel
// =====================================================================
__global__ __launch_bounds__(256) void pprgo_f32_kernel(
    const float* __restrict__ emb,
    const float* __restrict__ wei,
    const int*   __restrict__ nei,
    float*       __restrict__ out,
    int n_nodes)
{
    const int tid   = blockIdx.x * blockDim.x + threadIdx.x;
    const int group = tid >> 4;
    const int lane  = tid & 15;
    if (group >= n_nodes) return;
    const long base = (long)group * TOPK;
    const float w0 = wei[base + lane];
    const float w1 = wei[base + 16 + lane];
    const int   i0 = nei[base + lane];
    const int   i1 = nei[base + 16 + lane];
    const float m0 = (w0 != 0.0f) ? 1.0f : 0.0f;
    const float m1 = (w1 != 0.0f) ? 1.0f : 0.0f;
    float4 acc = make_float4(0.f, 0.f, 0.f, 0.f);
    float  cnt = 0.0f;
    #pragma unroll 8
    for (int k = 0; k < 16; ++k) {
        const int   j0 = __shfl(i0, k, 16);
        const float a0 = __shfl(m0, k, 16);
        const float4 r0 = *(const float4*)(emb + (size_t)j0 * EMB + lane * 4);
        acc.x += a0*r0.x; acc.y += a0*r0.y; acc.z += a0*r0.z; acc.w += a0*r0.w; cnt += a0;
        const int   j1 = __shfl(i1, k, 16);
        const float a1 = __shfl(m1, k, 16);
        const float4 r1 = *(const float4*)(emb + (size_t)j1 * EMB + lane * 4);
        acc.x += a1*r1.x; acc.y += a1*r1.y; acc.z += a1*r1.z; acc.w += a1*r1.w; cnt += a1;
    }
    const float sc = 1.0f / (cnt + 1e-12f);
    float4 o;
    o.x = acc.x*sc; o.y = acc.y*sc; o.z = acc.z*sc; o.w = acc.w*sc;
    *(float4*)(out + (size_t)group * EMB + lane * 4) = o;
}

extern "C" void kernel_launch(void* const* d_in, const int* in_sizes, int n_in,
                              void* d_out, int out_size, void* d_ws, size_t ws_size,
                              hipStream_t stream) {
    const float* emb = (const float*)d_in[0];   // [N, 64] fp32
    const float* wei = (const float*)d_in[1];   // [N, 32] fp32
    const int*   nei = (const int*)d_in[2];     // [N, 32] int32
    float*       out = (float*)d_out;           // [N, 1, 64] fp32

    const int n_nodes = in_sizes[1] / TOPK;     // 200000

    const size_t emb8_bytes = (size_t)(n_nodes + 1) * EMB;          // 12.8MB + 64B
    const size_t scale_off  = (emb8_bytes + 63) & ~(size_t)63;
    const size_t need_q8    = scale_off + (size_t)(n_nodes + 1) * sizeof(float) + 16;

    if (ws_size >= need_q8) {
        signed char* emb8   = (signed char*)d_ws;
        float*       scaleP = (float*)((char*)d_ws + scale_off);

        // one-pass per-row quant: 64 rows/block, covers rows 0..n_nodes (incl. zero row)
        const int q_blocks = (n_nodes + 1 + 63) / 64;                  // 3126
        quant_rowscale_kernel<<<q_blocks, 256, 0, stream>>>(
            emb, emb8, scaleP, n_nodes);

        const int g_blocks = (n_nodes * 8 + 255) / 256;                // 6250
        gather_q8s_kernel<<<g_blocks, 256, 0, stream>>>(
            emb8, scaleP, wei, nei, out, n_nodes);
    } else {
        const int threads = n_nodes * 16;
        pprgo_f32_kernel<<<(threads + 255) / 256, 256, 0, stream>>>(
            emb, wei, nei, out, n_nodes);
    }
}

// Round 3
// 224.960 us; speedup vs baseline: 1.7092x; 1.0017x over previous
//
#include <hip/hip_runtime.h>

#define TOPK 32
#define EMB 64

// =====================================================================
// k0: block-partial |max| over emb. 1024 partials, no atomics (deterministic).
// =====================================================================
__global__ __launch_bounds__(256) void absmax_partial_kernel(
    const float* __restrict__ emb, float* __restrict__ partial, int total4)
{
    const float4* src = (const float4*)emb;
    float m = 0.0f;
    for (int i = blockIdx.x * 256 + threadIdx.x; i < total4; i += gridDim.x * 256) {
        float4 v = src[i];
        m = fmaxf(m, fmaxf(fmaxf(fabsf(v.x), fabsf(v.y)),
                           fmaxf(fabsf(v.z), fabsf(v.w))));
    }
    __shared__ float red[256];
    red[threadIdx.x] = m;
    __syncthreads();
    for (int s = 128; s > 0; s >>= 1) {
        if (threadIdx.x < s) red[threadIdx.x] = fmaxf(red[threadIdx.x], red[threadIdx.x + s]);
        __syncthreads();
    }
    if (threadIdx.x == 0) partial[blockIdx.x] = red[0];
}

// =====================================================================
// k1: every block redundantly reduces the 1024 partials -> global max.
//  blocks [0, a_blocks): quantize emb fp32 -> int8 (16 elems/thread)
//  block  a_blocks:      store step (zero row kept for safety, 64B exactly)
// =====================================================================
__global__ __launch_bounds__(256) void quant_kernel(
    const float* __restrict__ emb, signed char* __restrict__ emb8,
    const float* __restrict__ partial, float* __restrict__ stepOut,
    int n_nodes, int a_blocks)
{
    const int t = threadIdx.x;
    __shared__ float red[256];
    float m = fmaxf(fmaxf(partial[t], partial[t + 256]),
                    fmaxf(partial[t + 512], partial[t + 768]));
    red[t] = m;
    __syncthreads();
    for (int s = 128; s > 0; s >>= 1) {
        if (t < s) red[t] = fmaxf(red[t], red[t + s]);
        __syncthreads();
    }
    const float maxv = fmaxf(red[0], 1e-20f);
    const float inv_step = 127.0f / maxv;

    if ((int)blockIdx.x < a_blocks) {
        const int gid = blockIdx.x * 256 + t;              // 16 elems per thread
        const int total16 = n_nodes * (EMB / 16);
        if (gid < total16) {
            const float4* src = (const float4*)emb + (size_t)gid * 4;
            unsigned int w[4];
            #pragma unroll
            for (int p = 0; p < 4; ++p) {
                float4 v = src[p];
                int q0 = (int)__builtin_rintf(fminf(fmaxf(v.x * inv_step, -127.f), 127.f));
                int q1 = (int)__builtin_rintf(fminf(fmaxf(v.y * inv_step, -127.f), 127.f));
                int q2 = (int)__builtin_rintf(fminf(fmaxf(v.z * inv_step, -127.f), 127.f));
                int q3 = (int)__builtin_rintf(fminf(fmaxf(v.w * inv_step, -127.f), 127.f));
                w[p] = (unsigned int)(q0 & 0xff) | ((unsigned int)(q1 & 0xff) << 8) |
                       ((unsigned int)(q2 & 0xff) << 16) | ((unsigned int)(q3 & 0xff) << 24);
            }
            ((int4*)emb8)[gid] = make_int4((int)w[0], (int)w[1], (int)w[2], (int)w[3]);
        }
    } else {
        // zero row = 64 bytes = exactly 4 int4 (unused by phased gather; kept harmless)
        if (t < 4)
            ((int4*)(emb8 + (size_t)n_nodes * EMB))[t] = make_int4(0, 0, 0, 0);
        if (t == 0) stepOut[0] = maxv / 127.0f;
    }
}

// =====================================================================
// k2: slice-phased gather, lean edition.
//  - 8 lanes per node (NPT=1): acc[8] int = 8 VGPRs/lane. NO launch_bounds
//    cap (R1's spill disaster), no per-row scale fetch (R2's fetch bloat).
//  - Per node: bucket its 32 neighbor indices by 2MB table slice into LDS
//    (intra-wave counting sort; R1 proved correctness of this choreography).
//    Masked neighbors are dropped -> no sentinel-row traffic.
//  - Slice loop outermost: resident blocks walk slices 0..6 in phase, so
//    each 2MB slice stays L2-resident while its uses occur.
//  - LDS padded [32][9] / [32][33]: group stride coprime with 32 banks
//    (R1's 8.5M conflicts came from power-of-2 strides).
//  - Exact int32 accumulate, fixed order -> deterministic, proven numerics.
// =====================================================================
#define ACC8(A, rx, ry) do {                                \
    A[0] += (int)(signed char)((rx) & 0xff);                \
    A[1] += (int)(signed char)(((rx) >> 8) & 0xff);         \
    A[2] += (int)(signed char)(((rx) >> 16) & 0xff);        \
    A[3] += ((int)(rx)) >> 24;                              \
    A[4] += (int)(signed char)((ry) & 0xff);                \
    A[5] += (int)(signed char)(((ry) >> 8) & 0xff);         \
    A[6] += (int)(signed char)(((ry) >> 16) & 0xff);        \
    A[7] += ((int)(ry)) >> 24; } while (0)

__global__ __launch_bounds__(256) void gather_q8_phased_kernel(
    const signed char* __restrict__ emb8,
    const float* __restrict__ wei,
    const int*   __restrict__ nei,
    const float* __restrict__ stepPtr,
    float*       __restrict__ out,
    int n_nodes, int sshift, int nslices)
{
    __shared__ int s_cnt[32][9];     // slice counters/offsets, padded (1.2KB)
    __shared__ int s_lst[32][33];    // bucketed byte offsets, padded (4.2KB)

    const int gl   = threadIdx.x >> 3;   // node-group within block, 0..31
    const int lane = threadIdx.x & 7;
    const int n    = blockIdx.x * 32 + gl;
    if (n >= n_nodes) return;            // group-uniform; no barriers used below

    // zero own group's counters (same wave -> no sync needed)
    if (lane < 8) {
        s_cnt[gl][lane] = 0;
    }

    // load nei/wei; masked -> -1 (dropped)
    const long base = (long)n * TOPK;
    const int4   j4 = *(const int4*)(nei + base + lane * 4);
    const float4 w4 = *(const float4*)(wei + base + lane * 4);
    int jm[4];
    jm[0] = (w4.x != 0.0f) ? j4.x : -1;
    jm[1] = (w4.y != 0.0f) ? j4.y : -1;
    jm[2] = (w4.z != 0.0f) ? j4.z : -1;
    jm[3] = (w4.w != 0.0f) ? j4.w : -1;

    // pass 1: per-slice counts (LDS atomics, intra-wave, proven in R1)
    #pragma unroll
    for (int c = 0; c < 4; ++c) {
        const int v = jm[c];
        if (v >= 0) atomicAdd(&s_cnt[gl][v >> sshift], 1);
    }

    // lane 0: exclusive prefix -> start offsets; tot = valid count
    int tot = 0;
    if (lane == 0) {
        int run = 0;
        for (int s = 0; s < nslices; ++s) {
            const int c = s_cnt[gl][s];
            s_cnt[gl][s] = run;
            run += c;
        }
        tot = run;
    }
    tot = __shfl(tot, 0, 8);

    // pass 2: place pre-shifted byte offsets (j*64)
    #pragma unroll
    for (int c = 0; c < 4; ++c) {
        const int v = jm[c];
        if (v >= 0) {
            const int pos = atomicAdd(&s_cnt[gl][v >> sshift], 1);
            s_lst[gl][pos] = v << 6;
        }
    }
    // s_cnt[gl][s] now = END offset of slice s

    int acc[8] = {0, 0, 0, 0, 0, 0, 0, 0};
    const signed char* ebase = emb8 + lane * 8;

    for (int s = 0; s < nslices; ++s) {
        int i = (s == 0) ? 0 : s_cnt[gl][s - 1];
        const int e = s_cnt[gl][s];
        for (; i + 4 <= e; i += 4) {           // 4-wide chunks for MLP
            const int o0 = s_lst[gl][i];
            const int o1 = s_lst[gl][i + 1];
            const int o2 = s_lst[gl][i + 2];
            const int o3 = s_lst[gl][i + 3];
            const uint2 r0 = *(const uint2*)(ebase + o0);
            const uint2 r1 = *(const uint2*)(ebase + o1);
            const uint2 r2 = *(const uint2*)(ebase + o2);
            const uint2 r3 = *(const uint2*)(ebase + o3);
            ACC8(acc, r0.x, r0.y);
            ACC8(acc, r1.x, r1.y);
            ACC8(acc, r2.x, r2.y);
            ACC8(acc, r3.x, r3.y);
        }
        for (; i < e; ++i) {
            const int o = s_lst[gl][i];
            const uint2 r = *(const uint2*)(ebase + o);
            ACC8(acc, r.x, r.y);
        }
    }

    const float step = stepPtr[0];
    const float mlt = step / ((float)tot + 1e-12f);
    float4 o0, o1;
    o0.x = acc[0] * mlt; o0.y = acc[1] * mlt; o0.z = acc[2] * mlt; o0.w = acc[3] * mlt;
    o1.x = acc[4] * mlt; o1.y = acc[5] * mlt; o1.z = acc[6] * mlt; o1.w = acc[7] * mlt;
    float* op = out + (size_t)n * EMB + lane * 8;
    *(float4*)op       = o0;
    *(float4*)(op + 4) = o1;
}

// =====================================================================
// Fallback (tiny ws): verified R0 fp32 kernel
// =====================================================================
__global__ __launch_bounds__(256) void pprgo_f32_kernel(
    const float* __restrict__ emb,
    const float* __restrict__ wei,
    const int*   __restrict__ nei,
    float*       __restrict__ out,
    int n_nodes)
{
    const int tid   = blockIdx.x * blockDim.x + threadIdx.x;
    const int group = tid >> 4;
    const int lane  = tid & 15;
    if (group >= n_nodes) return;
    const long base = (long)group * TOPK;
    const float w0 = wei[base + lane];
    const float w1 = wei[base + 16 + lane];
    const int   i0 = nei[base + lane];
    const int   i1 = nei[base + 16 + lane];
    const float m0 = (w0 != 0.0f) ? 1.0f : 0.0f;
    const float m1 = (w1 != 0.0f) ? 1.0f : 0.0f;
    float4 acc = make_float4(0.f, 0.f, 0.f, 0.f);
    float  cnt = 0.0f;
    #pragma unroll 8
    for (int k = 0; k < 16; ++k) {
        const int   j0 = __shfl(i0, k, 16);
        const float a0 = __shfl(m0, k, 16);
        const float4 r0 = *(const float4*)(emb + (size_t)j0 * EMB + lane * 4);
        acc.x += a0*r0.x; acc.y += a0*r0.y; acc.z += a0*r0.z; acc.w += a0*r0.w; cnt += a0;
        const int   j1 = __shfl(i1, k, 16);
        const float a1 = __shfl(m1, k, 16);
        const float4 r1 = *(const float4*)(emb + (size_t)j1 * EMB + lane * 4);
        acc.x += a1*r1.x; acc.y += a1*r1.y; acc.z += a1*r1.z; acc.w += a1*r1.w; cnt += a1;
    }
    const float sc = 1.0f / (cnt + 1e-12f);
    float4 o;
    o.x = acc.x*sc; o.y = acc.y*sc; o.z = acc.z*sc; o.w = acc.w*sc;
    *(float4*)(out + (size_t)group * EMB + lane * 4) = o;
}

extern "C" void kernel_launch(void* const* d_in, const int* in_sizes, int n_in,
                              void* d_out, int out_size, void* d_ws, size_t ws_size,
                              hipStream_t stream) {
    const float* emb = (const float*)d_in[0];   // [N, 64] fp32
    const float* wei = (const float*)d_in[1];   // [N, 32] fp32
    const int*   nei = (const int*)d_in[2];     // [N, 32] int32
    float*       out = (float*)d_out;           // [N, 1, 64] fp32

    const int n_nodes = in_sizes[1] / TOPK;     // 200000

    const size_t emb8_bytes  = (size_t)(n_nodes + 1) * EMB;            // 12.8MB + 64B
    const size_t partial_off = (emb8_bytes + 15) & ~(size_t)15;
    const size_t need_q8     = partial_off + 1024 * sizeof(float) + 16;

    if (ws_size >= need_q8) {
        signed char* emb8    = (signed char*)d_ws;
        float*       partial = (float*)((char*)d_ws + partial_off);
        float*       stepP   = partial + 1024;

        const int total4 = n_nodes * EMB / 4;
        absmax_partial_kernel<<<1024, 256, 0, stream>>>(emb, partial, total4);

        const int a_blocks = (n_nodes * (EMB / 16) + 255) / 256;       // 3125
        quant_kernel<<<a_blocks + 1, 256, 0, stream>>>(
            emb, emb8, partial, stepP, n_nodes, a_blocks);

        // slice-phased gather: 2^sshift-row slices (<=2MB, <=8 slices)
        int sshift = 15;
        while (((n_nodes + (1 << sshift) - 1) >> sshift) > 8) ++sshift;
        const int nslices = (n_nodes + (1 << sshift) - 1) >> sshift;   // 7
        const int g_blocks = (n_nodes + 31) / 32;                      // 6250
        gather_q8_phased_kernel<<<g_blocks, 256, 0, stream>>>(
            emb8, wei, nei, stepP, out, n_nodes, sshift, nslices);
    } else {
        const int threads = n_nodes * 16;
        pprgo_f32_kernel<<<(threads + 255) / 256, 256, 0, stream>>>(
            emb, wei, nei, out, n_nodes);
    }
}